// Round 1
// baseline (53671.661 us; speedup 1.0000x reference)
//
#include <hip/hip_runtime.h>

// ---------------------------------------------------------------------------
// RAE forward, fp32 SIMT baseline.
// Shapes: B=64, L=64, I=256, E=1024, h1=640, h2=1536, T_ENC=24.
// All GEMMs: M % 64 == 0, N % 64 == 0, K % 8 == 0  -> no bounds checks.
// ---------------------------------------------------------------------------

__device__ __forceinline__ float ts_val(int t, int rc) {
    // e[0] = rc; e[idx] = 1.0 (idx >= 1 always for rc >= 1)
    int idx = (rc == 1) ? 1 : (rc == 2) ? 2 : (rc <= 4) ? 3 : ((rc + 10) / 3 - 1);
    if (t == idx) return 1.0f;
    if (t == 0)   return (float)rc;
    return 0.0f;
}

// ----------------------------- GEMM ----------------------------------------
// C[M,N] = act(A[M,K] @ W[K,N] + bias[N]);  act: 0 = none, 1 = relu
// 64x64 tile, BK=8, 256 threads, 4x4 per thread.
__global__ __launch_bounds__(256) void gemm_bias_act(
    const float* __restrict__ A, const float* __restrict__ W,
    const float* __restrict__ bias, float* __restrict__ C,
    int M, int N, int K, int act)
{
    __shared__ float As[8][64];
    __shared__ float Bs[8][64];

    const int bm = blockIdx.y * 64;
    const int bn = blockIdx.x * 64;
    const int tid = threadIdx.x;
    const int tx = tid & 15;
    const int ty = tid >> 4;

    float acc[4][4] = {};

    for (int k0 = 0; k0 < K; k0 += 8) {
        #pragma unroll
        for (int i = 0; i < 2; i++) {
            int e = tid + i * 256;            // 512 elems of A tile (64x8)
            int am = e >> 3, ak = e & 7;
            As[ak][am] = A[(size_t)(bm + am) * K + k0 + ak];
        }
        #pragma unroll
        for (int i = 0; i < 2; i++) {
            int e = tid + i * 256;            // 512 elems of B tile (8x64)
            int bk = e >> 6, bc = e & 63;
            Bs[bk][bc] = W[(size_t)(k0 + bk) * N + bn + bc];
        }
        __syncthreads();
        #pragma unroll
        for (int kk = 0; kk < 8; kk++) {
            float a0[4], b0[4];
            #pragma unroll
            for (int i = 0; i < 4; i++) a0[i] = As[kk][ty * 4 + i];
            #pragma unroll
            for (int j = 0; j < 4; j++) b0[j] = Bs[kk][tx * 4 + j];
            #pragma unroll
            for (int i = 0; i < 4; i++)
                #pragma unroll
                for (int j = 0; j < 4; j++)
                    acc[i][j] = fmaf(a0[i], b0[j], acc[i][j]);
        }
        __syncthreads();
    }

    #pragma unroll
    for (int i = 0; i < 4; i++) {
        int m = bm + ty * 4 + i;
        #pragma unroll
        for (int j = 0; j < 4; j++) {
            int n = bn + tx * 4 + j;
            float v = acc[i][j] + bias[n];
            if (act) v = fmaxf(v, 0.0f);
            C[(size_t)m * N + n] = v;
        }
    }
}

// --------------------------- LayerNorm + ReLU -------------------------------
// One block (256 threads) per row; Wd in {1024, 1536}. in/out may alias.
__global__ __launch_bounds__(256) void ln_relu_k(
    const float* __restrict__ in, float* __restrict__ out,
    const float* __restrict__ gw, const float* __restrict__ bw, int Wd)
{
    const int row = blockIdx.x;
    const float* x = in + (size_t)row * Wd;
    float* y = out + (size_t)row * Wd;
    const int nv = Wd >> 8;                  // 4 or 6 elements per thread

    float vals[6];
    float s = 0.f, s2 = 0.f;
    for (int i = 0; i < nv; i++) {
        float v = x[threadIdx.x + (i << 8)];
        vals[i] = v;
        s += v; s2 += v * v;
    }
    // wave (64-lane) butterfly reduce
    for (int o = 1; o < 64; o <<= 1) {
        s  += __shfl_xor(s, o);
        s2 += __shfl_xor(s2, o);
    }
    __shared__ float red[2][4];
    const int wv = threadIdx.x >> 6;
    if ((threadIdx.x & 63) == 0) { red[0][wv] = s; red[1][wv] = s2; }
    __syncthreads();
    s  = red[0][0] + red[0][1] + red[0][2] + red[0][3];
    s2 = red[1][0] + red[1][1] + red[1][2] + red[1][3];

    const float inv = 1.0f / (float)Wd;
    const float mean = s * inv;
    const float var = s2 * inv - mean * mean;
    const float rstd = rsqrtf(var + 1e-5f);

    for (int i = 0; i < nv; i++) {
        int c = threadIdx.x + (i << 8);
        float v = (vals[i] - mean) * rstd * gw[c] + bw[c];
        y[c] = fmaxf(v, 0.0f);
    }
}

// ------------------------------ concat kernels ------------------------------
// encode: cat[b,l,:] = [x[b,l,:1024] | x[b,l+1,:1024] | ts(rc)]  (width 2072)
__global__ __launch_bounds__(256) void enc_cat_k(
    const float* __restrict__ x, float* __restrict__ cat, int Lo, int rc)
{
    int c = blockIdx.x * 256 + threadIdx.x;
    if (c >= 2072) return;
    int row = blockIdx.y;                    // b*Lo + l
    int l = row % Lo, b = row / Lo;
    int Li = Lo + 1;
    float v;
    if (c < 1024)       v = x[(size_t)(b * Li + l) * 1024 + c];
    else if (c < 2048)  v = x[(size_t)(b * Li + l + 1) * 1024 + (c - 1024)];
    else                v = ts_val(c - 2048, rc);
    cat[(size_t)row * 2072 + c] = v;
}

// decode: cat[row,:] = [x[row,:1024] | ts(rc)]  (width 1048)
__global__ __launch_bounds__(256) void dec_cat_k(
    const float* __restrict__ x, float* __restrict__ cat, int rc)
{
    int c = blockIdx.x * 256 + threadIdx.x;
    if (c >= 1048) return;
    int row = blockIdx.y;
    float v = (c < 1024) ? x[(size_t)row * 1024 + c] : ts_val(c - 1024, rc);
    cat[(size_t)row * 1048 + c] = v;
}

// decode overlap-combine: g[B,Li,2048] -> y[B,Li+1,1024]
__global__ __launch_bounds__(256) void dec_combine_k(
    const float* __restrict__ g, float* __restrict__ y, int Li)
{
    int c = blockIdx.x * 256 + threadIdx.x;  // < 1024
    int row = blockIdx.y;                    // b*(Li+1) + j
    int Lo = Li + 1;
    int b = row / Lo, j = row - b * Lo;
    const float* gb = g + (size_t)(b * Li) * 2048;
    float v;
    if (j == 0)        v = gb[c];
    else if (j == Li)  v = gb[(size_t)(Li - 1) * 2048 + 1024 + c];
    else               v = 0.5f * (gb[(size_t)(j - 1) * 2048 + 1024 + c] +
                                   gb[(size_t)j * 2048 + c]);
    y[(size_t)row * 1024 + c] = v;
}

// ------------------------------ orchestration -------------------------------
extern "C" void kernel_launch(void* const* d_in, const int* in_sizes, int n_in,
                              void* d_out, int out_size, void* d_ws, size_t ws_size,
                              hipStream_t stream)
{
    const float* xin    = (const float*)d_in[0];
    const float* se_w1  = (const float*)d_in[1];
    const float* se_b1  = (const float*)d_in[2];
    const float* se_w2  = (const float*)d_in[3];
    const float* se_b2  = (const float*)d_in[4];
    const float* enc_w1 = (const float*)d_in[5];
    const float* enc_b1 = (const float*)d_in[6];
    const float* enc_g1 = (const float*)d_in[7];
    const float* enc_bb1= (const float*)d_in[8];
    const float* enc_w2 = (const float*)d_in[9];
    const float* enc_b2 = (const float*)d_in[10];
    const float* enc_g2 = (const float*)d_in[11];
    const float* enc_bb2= (const float*)d_in[12];
    const float* dec_w1 = (const float*)d_in[13];
    const float* dec_b1 = (const float*)d_in[14];
    const float* dec_g1 = (const float*)d_in[15];
    const float* dec_bb1= (const float*)d_in[16];
    const float* dec_w2 = (const float*)d_in[17];
    const float* dec_b2 = (const float*)d_in[18];
    const float* d2_g   = (const float*)d_in[19];
    const float* d2_b   = (const float*)d_in[20];
    const float* de_w1  = (const float*)d_in[21];
    const float* de_b1  = (const float*)d_in[22];
    const float* de_w2  = (const float*)d_in[23];
    const float* de_b2  = (const float*)d_in[24];

    float* ws  = (float*)d_ws;
    float* X   = ws;                          // 64*64*1024           = 4,194,304 f
    float* CAT = ws + 4194304;                // 64*63*2072           = 8,354,304 f
    float* H   = ws + 4194304 + 8354304;      // 64*63*1536           = 6,193,152 f
    // total 18,741,760 floats = ~75 MB

    auto gemm = [&](const float* A, const float* W, const float* b, float* C,
                    int M, int N, int K, int act) {
        dim3 grid(N / 64, M / 64);
        gemm_bias_act<<<grid, 256, 0, stream>>>(A, W, b, C, M, N, K, act);
    };
    auto ln = [&](const float* in, float* out, const float* g, const float* b,
                  int rows, int Wd) {
        ln_relu_k<<<rows, 256, 0, stream>>>(in, out, g, b, Wd);
    };

    // ---- scale_embedding: x = relu(relu(x@se_w1+b)@se_w2+b) ----
    gemm(xin, se_w1, se_b1, H, 4096, 640, 256, 1);
    gemm(H, se_w2, se_b2, X, 4096, 1024, 640, 1);

    // ---- encode: 63 pairwise-merge steps ----
    for (int rc = 1; rc <= 63; rc++) {
        int Lo = 64 - rc;
        enc_cat_k<<<dim3(9, 64 * Lo), 256, 0, stream>>>(X, CAT, Lo, rc);
        gemm(CAT, enc_w1, enc_b1, H, 64 * Lo, 1536, 2072, 0);
        ln(H, H, enc_g1, enc_bb1, 64 * Lo, 1536);
        gemm(H, enc_w2, enc_b2, X, 64 * Lo, 1024, 1536, 0);
        ln(X, X, enc_g2, enc_bb2, 64 * Lo, 1024);
    }

    // ---- decode first step: [B,1,E] -> [B,2,E] ----
    dec_cat_k<<<dim3(5, 64), 256, 0, stream>>>(X, CAT, 63);
    gemm(CAT, dec_w1, dec_b1, H, 64, 1536, 1048, 0);
    ln(H, H, dec_g1, dec_bb1, 64, 1536);
    gemm(H, dec_w2, dec_b2, CAT, 64, 2048, 1536, 0);   // g = [64, 2048]
    ln(CAT, X, d2_g, d2_b, 128, 1024);                 // reshape view [128,1024]

    // ---- decode loop ----
    for (int rc = 62; rc >= 1; rc--) {
        int Li = 64 - rc;
        dec_cat_k<<<dim3(5, 64 * Li), 256, 0, stream>>>(X, CAT, rc);
        gemm(CAT, dec_w1, dec_b1, H, 64 * Li, 1536, 1048, 0);
        ln(H, H, dec_g1, dec_bb1, 64 * Li, 1536);
        gemm(H, dec_w2, dec_b2, CAT, 64 * Li, 2048, 1536, 0);  // g
        dec_combine_k<<<dim3(4, 64 * (Li + 1)), 256, 0, stream>>>(CAT, X, Li);
        ln(X, X, d2_g, d2_b, 64 * (Li + 1), 1024);
    }

    // ---- descale_embedding ----
    gemm(X, de_w1, de_b1, H, 4096, 640, 1024, 1);
    gemm(H, de_w2, de_b2, (float*)d_out, 4096, 256, 640, 0);
}

// Round 2
// 36292.303 us; speedup vs baseline: 1.4789x; 1.4789x over previous
//
#include <hip/hip_runtime.h>

// ---------------------------------------------------------------------------
// RAE forward with split-f16 MFMA GEMMs.
// Every fp32 tensor value v is carried as f16 pair (hi, lo) with
//   v ~= hi + lo * 2^-12   (lo stored pre-scaled by 2^12)
// GEMM: C = A@W ~= Ah@Wh + (Al@Wh + Ah@Wl) * 2^-12   (3 MFMA products)
// ---------------------------------------------------------------------------

typedef _Float16 f16;
typedef _Float16 half8 __attribute__((ext_vector_type(8)));
typedef float floatx4 __attribute__((ext_vector_type(4)));

#define LO_SC   4096.0f
#define LO_ISC  2.44140625e-4f

__device__ __forceinline__ void gld_lds16(const f16* g, f16* l) {
    __builtin_amdgcn_global_load_lds(
        (const __attribute__((address_space(1))) void*)g,
        (__attribute__((address_space(3))) void*)l, 16, 0, 0);
}

__device__ __forceinline__ float pair_val(const f16* ph, const f16* pl, size_t i) {
    return (float)ph[i] + (float)pl[i] * LO_ISC;
}

__device__ __forceinline__ void split_store(float v, f16* ph, f16* pl, size_t i) {
    f16 h = (f16)v;
    ph[i] = h;
    pl[i] = (f16)((v - (float)h) * LO_SC);
}

// ----------------------------- GEMM ----------------------------------------
// MODE 0: plain A (pair arrays, row stride lda)
// MODE 1: enc-cat: logical row r -> b=r/Lo,l=r%Lo; A row = b*Li+l, 2048-wide
//         contiguous window; k >= 2048 -> ts table
// MODE 2: dec-cat: A row = r; k >= 1024 -> ts table
// OUT 0: pair store; OUT 1: relu + pair store; OUT 2: fp32 store
// Tile 128x128, BK=32, 256 threads (4 waves), each wave a 64x64 quadrant.
template<int MODE, int OUT>
__global__ __launch_bounds__(256, 2) void gemm_split(
    const f16* __restrict__ Ahi, const f16* __restrict__ Alo, int lda,
    const f16* __restrict__ Whi, const f16* __restrict__ Wlo,   // [N][K] transposed
    const float* __restrict__ bias,
    f16* __restrict__ Chi, f16* __restrict__ Clo, float* __restrict__ Cf,
    int M, int N, int K, int Kpad, int kbound, int Lo, int Li,
    const f16* __restrict__ tsrow, const f16* __restrict__ zrow)
{
    __shared__ __align__(16) f16 sAh[4][128][8];
    __shared__ __align__(16) f16 sAl[4][128][8];
    __shared__ __align__(16) f16 sWh[4][128][8];
    __shared__ __align__(16) f16 sWl[4][128][8];

    const int tid  = threadIdx.x;
    const int lane = tid & 63;
    const int wid  = tid >> 6;
    const int bm   = blockIdx.y * 128;
    const int bn   = blockIdx.x * 128;

    // staging: wave `wid` fills kchunk = wid; slots it=0,1 -> row/col = it*64+lane
    const f16* aph[2]; const f16* apl[2];
    const f16* wph[2]; const f16* wpl[2];
    #pragma unroll
    for (int it = 0; it < 2; it++) {
        int r = bm + it * 64 + lane;
        if (r > M - 1) r = M - 1;
        int arow;
        if (MODE == 1) { int b = r / Lo; int l = r - b * Lo; arow = b * Li + l; }
        else arow = r;
        aph[it] = Ahi + (size_t)arow * lda;
        apl[it] = Alo + (size_t)arow * lda;
        int col = bn + it * 64 + lane;          // N % 128 == 0 -> in range
        wph[it] = Whi + (size_t)col * K;
        wpl[it] = Wlo + (size_t)col * K;
    }

    floatx4 acc1[4][4] = {};
    floatx4 acc2[4][4] = {};

    const int kw0 = wid * 8;
    for (int k0 = 0; k0 < Kpad; k0 += 32) {
        __syncthreads();                         // previous tile fully consumed
        const int ka = k0 + kw0;
        int kwc = ka; if (kwc > K - 8) kwc = K - 8;   // W k-clamp (A side is 0 there)
        #pragma unroll
        for (int it = 0; it < 2; it++) {
            const f16* sh; const f16* sl;
            if (MODE == 0 || ka < kbound) { sh = aph[it] + ka; sl = apl[it] + ka; }
            else { sh = tsrow + (ka - kbound); sl = zrow; }
            gld_lds16(sh,            &sAh[wid][it * 64][0]);
            gld_lds16(sl,            &sAl[wid][it * 64][0]);
            gld_lds16(wph[it] + kwc, &sWh[wid][it * 64][0]);
            gld_lds16(wpl[it] + kwc, &sWl[wid][it * 64][0]);
        }
        __syncthreads();                         // compiler drains vmcnt before barrier

        const int kc = lane >> 4;
        const int fr = lane & 15;
        const int wr = (wid >> 1) * 64;
        const int wc = (wid & 1) * 64;
        half8 ah[4], al[4], wh[4], wl[4];
        #pragma unroll
        for (int m = 0; m < 4; m++) {
            ah[m] = *(const half8*)&sAh[kc][wr + m * 16 + fr][0];
            al[m] = *(const half8*)&sAl[kc][wr + m * 16 + fr][0];
        }
        #pragma unroll
        for (int n = 0; n < 4; n++) {
            wh[n] = *(const half8*)&sWh[kc][wc + n * 16 + fr][0];
            wl[n] = *(const half8*)&sWl[kc][wc + n * 16 + fr][0];
        }
        #pragma unroll
        for (int m = 0; m < 4; m++)
            #pragma unroll
            for (int n = 0; n < 4; n++) {
                acc1[m][n] = __builtin_amdgcn_mfma_f32_16x16x32_f16(ah[m], wh[n], acc1[m][n], 0, 0, 0);
                acc2[m][n] = __builtin_amdgcn_mfma_f32_16x16x32_f16(al[m], wh[n], acc2[m][n], 0, 0, 0);
                acc2[m][n] = __builtin_amdgcn_mfma_f32_16x16x32_f16(ah[m], wl[n], acc2[m][n], 0, 0, 0);
            }
    }

    // epilogue: C/D frag layout col = lane&15, row = (lane>>4)*4 + j
    const int fr  = lane & 15;
    const int q4  = (lane >> 4) * 4;
    const int wr  = (wid >> 1) * 64;
    const int wc  = (wid & 1) * 64;
    #pragma unroll
    for (int n = 0; n < 4; n++) {
        const int gcol = bn + wc + n * 16 + fr;
        const float bv = bias[gcol];
        #pragma unroll
        for (int m = 0; m < 4; m++) {
            #pragma unroll
            for (int j = 0; j < 4; j++) {
                const int grow = bm + wr + m * 16 + q4 + j;
                if (grow < M) {
                    float v = acc1[m][n][j] + acc2[m][n][j] * LO_ISC + bv;
                    if (OUT == 1) v = fmaxf(v, 0.0f);
                    const size_t o = (size_t)grow * N + gcol;
                    if (OUT == 2) Cf[o] = v;
                    else {
                        f16 h = (f16)v;
                        Chi[o] = h;
                        Clo[o] = (f16)((v - (float)h) * LO_SC);
                    }
                }
            }
        }
    }
}

// --------------------------- LayerNorm + ReLU on pairs ----------------------
__global__ __launch_bounds__(256) void ln_pair_k(
    const f16* __restrict__ ih, const f16* __restrict__ il,
    f16* __restrict__ oh, f16* __restrict__ ol,
    const float* __restrict__ gw, const float* __restrict__ bw, int Wd)
{
    const size_t base = (size_t)blockIdx.x * Wd;
    const int nv = Wd >> 8;
    float vals[6], s = 0.f, s2 = 0.f;
    for (int i = 0; i < nv; i++) {
        int c = threadIdx.x + (i << 8);
        float v = pair_val(ih, il, base + c);
        vals[i] = v; s += v; s2 += v * v;
    }
    for (int o = 1; o < 64; o <<= 1) { s += __shfl_xor(s, o); s2 += __shfl_xor(s2, o); }
    __shared__ float red[2][4];
    if ((threadIdx.x & 63) == 0) { red[0][threadIdx.x >> 6] = s; red[1][threadIdx.x >> 6] = s2; }
    __syncthreads();
    s  = red[0][0] + red[0][1] + red[0][2] + red[0][3];
    s2 = red[1][0] + red[1][1] + red[1][2] + red[1][3];
    const float inv = 1.0f / (float)Wd;
    const float mean = s * inv;
    const float rstd = rsqrtf(s2 * inv - mean * mean + 1e-5f);
    for (int i = 0; i < nv; i++) {
        int c = threadIdx.x + (i << 8);
        float v = (vals[i] - mean) * rstd * gw[c] + bw[c];
        v = fmaxf(v, 0.0f);
        split_store(v, oh, ol, base + c);
    }
}

// ------------------- decode overlap-combine + LN + ReLU ---------------------
// G pair [nb*Liv, 2048] -> X pair rows [nb*(Liv+1), 1024]
__global__ __launch_bounds__(256) void comb_ln_k(
    const f16* __restrict__ gh, const f16* __restrict__ gl,
    f16* __restrict__ oh, f16* __restrict__ ol,
    const float* __restrict__ gw, const float* __restrict__ bw, int Liv)
{
    const int row = blockIdx.x;
    const int Lp = Liv + 1;
    const int b = row / Lp, j = row - b * Lp;
    float vals[4], s = 0.f, s2 = 0.f;
    for (int i = 0; i < 4; i++) {
        int c = threadIdx.x + (i << 8);
        float v;
        if (j == 0)          v = pair_val(gh, gl, (size_t)(b * Liv) * 2048 + c);
        else if (j == Liv)   v = pair_val(gh, gl, (size_t)(b * Liv + Liv - 1) * 2048 + 1024 + c);
        else v = 0.5f * (pair_val(gh, gl, (size_t)(b * Liv + j - 1) * 2048 + 1024 + c) +
                         pair_val(gh, gl, (size_t)(b * Liv + j) * 2048 + c));
        vals[i] = v; s += v; s2 += v * v;
    }
    for (int o = 1; o < 64; o <<= 1) { s += __shfl_xor(s, o); s2 += __shfl_xor(s2, o); }
    __shared__ float red[2][4];
    if ((threadIdx.x & 63) == 0) { red[0][threadIdx.x >> 6] = s; red[1][threadIdx.x >> 6] = s2; }
    __syncthreads();
    s  = red[0][0] + red[0][1] + red[0][2] + red[0][3];
    s2 = red[1][0] + red[1][1] + red[1][2] + red[1][3];
    const float mean = s * 9.765625e-4f;
    const float rstd = rsqrtf(s2 * 9.765625e-4f - mean * mean + 1e-5f);
    const size_t ob = (size_t)row * 1024;
    for (int i = 0; i < 4; i++) {
        int c = threadIdx.x + (i << 8);
        float v = (vals[i] - mean) * rstd * gw[c] + bw[c];
        v = fmaxf(v, 0.0f);
        split_store(v, oh, ol, ob + c);
    }
}

// ---------------- weight transpose + split: W[K][N] -> Wt[N][K] -------------
__global__ __launch_bounds__(256) void wt_split_k(
    const float* __restrict__ W, f16* __restrict__ Th, f16* __restrict__ Tl,
    int K, int N)
{
    __shared__ float t[64][65];
    const int k0 = blockIdx.x * 64, n0 = blockIdx.y * 64;
    {
        const int j = threadIdx.x & 63, i0 = (threadIdx.x >> 6) * 16;
        for (int ii = 0; ii < 16; ii++) {
            int k = k0 + i0 + ii;
            t[i0 + ii][j] = (k < K) ? W[(size_t)k * N + n0 + j] : 0.f;
        }
    }
    __syncthreads();
    const int i = threadIdx.x & 63, j0 = (threadIdx.x >> 6) * 16;
    const int k = k0 + i;
    if (k < K) {
        for (int jj = 0; jj < 16; jj++) {
            float v = t[i][j0 + jj];
            f16 h = (f16)v;
            const size_t o = (size_t)(n0 + j0 + jj) * K + k;
            Th[o] = h;
            Tl[o] = (f16)((v - (float)h) * LO_SC);
        }
    }
}

// --------------------------- misc small kernels -----------------------------
__global__ void split_x_k(const float* __restrict__ x, f16* __restrict__ h,
                          f16* __restrict__ l, int n) {
    int i = blockIdx.x * 256 + threadIdx.x;
    if (i < n) split_store(x[i], h, l, i);
}

__global__ void ts_init_k(f16* __restrict__ ts, f16* __restrict__ z) {
    int e = blockIdx.x * 256 + threadIdx.x;
    if (e < 2048) {
        int rc = e >> 5, c = e & 31;
        float v = 0.f;
        if (rc >= 1) {
            int idx = (rc == 1) ? 1 : (rc == 2) ? 2 : (rc <= 4) ? 3 : ((rc + 10) / 3 - 1);
            if (c == 0) v = (float)rc;
            else if (c == idx) v = 1.f;
        }
        ts[e] = (f16)v;
    }
    if (e < 32) z[e] = (f16)0.f;
}

// ------------------------------ orchestration -------------------------------
extern "C" void kernel_launch(void* const* d_in, const int* in_sizes, int n_in,
                              void* d_out, int out_size, void* d_ws, size_t ws_size,
                              hipStream_t stream)
{
    const float* xin    = (const float*)d_in[0];
    const float* se_w1  = (const float*)d_in[1];
    const float* se_b1  = (const float*)d_in[2];
    const float* se_w2  = (const float*)d_in[3];
    const float* se_b2  = (const float*)d_in[4];
    const float* enc_w1 = (const float*)d_in[5];
    const float* enc_b1 = (const float*)d_in[6];
    const float* enc_g1 = (const float*)d_in[7];
    const float* enc_bb1= (const float*)d_in[8];
    const float* enc_w2 = (const float*)d_in[9];
    const float* enc_b2 = (const float*)d_in[10];
    const float* enc_g2 = (const float*)d_in[11];
    const float* enc_bb2= (const float*)d_in[12];
    const float* dec_w1 = (const float*)d_in[13];
    const float* dec_b1 = (const float*)d_in[14];
    const float* dec_g1 = (const float*)d_in[15];
    const float* dec_bb1= (const float*)d_in[16];
    const float* dec_w2 = (const float*)d_in[17];
    const float* dec_b2 = (const float*)d_in[18];
    const float* d2_g   = (const float*)d_in[19];
    const float* d2_b   = (const float*)d_in[20];
    const float* de_w1  = (const float*)d_in[21];
    const float* de_b1  = (const float*)d_in[22];
    const float* de_w2  = (const float*)d_in[23];
    const float* de_b2  = (const float*)d_in[24];

    f16* ws = (f16*)d_ws;
    f16* Xh = ws;                        // 4,194,304
    f16* Xl = Xh + 4194304;
    f16* Hh = Xl + 4194304;              // 3,096,576
    f16* Hl = Hh + 3096576;
    f16* Gh = Hl + 3096576;              // 4,128,768
    f16* Gl = Gh + 4128768;
    f16* WR = Gl + 4128768;              // 9,510,912 (phase-reused weights)
    f16* TS = WR + 9510912;              // 2048
    f16* ZB = TS + 2048;                 // 32       (total ~64.7 MB)

    ts_init_k<<<8, 256, 0, stream>>>(TS, ZB);

    auto wt = [&](const float* W, int K, int N, f16* Th, f16* Tl) {
        wt_split_k<<<dim3((K + 63) / 64, N / 64), 256, 0, stream>>>(W, Th, Tl, K, N);
    };
    auto ln = [&](const f16* ih, const f16* il, f16* oh, f16* ol,
                  const float* g, const float* b, int rows, int Wd) {
        ln_pair_k<<<rows, 256, 0, stream>>>(ih, il, oh, ol, g, b, Wd);
    };

    #define GEMM(MODE, OUT, Ah, Al, lda, Wh, Wl, bias, Ch, Cl, Cf, M, N, K, Kpad, kb, Lo, Li, tsr) \
        gemm_split<MODE, OUT><<<dim3((N) / 128, ((M) + 127) / 128), 256, 0, stream>>>( \
            Ah, Al, lda, Wh, Wl, bias, Ch, Cl, Cf, M, N, K, Kpad, kb, Lo, Li, tsr, ZB)

    // ---- scale_embedding ----
    {
        f16* W1h = WR;            f16* W1l = W1h + 163840;
        f16* W2h = W1l + 163840;  f16* W2l = W2h + 655360;
        wt(se_w1, 256, 640, W1h, W1l);
        wt(se_w2, 640, 1024, W2h, W2l);
        split_x_k<<<4096, 256, 0, stream>>>(xin, Gh, Gl, 1048576);
        GEMM(0, 1, Gh, Gl, 256, W1h, W1l, se_b1, Hh, Hl, (float*)0, 4096, 640, 256, 256, 256, 0, 0, ZB);
        GEMM(0, 1, Hh, Hl, 640, W2h, W2l, se_b2, Xh, Xl, (float*)0, 4096, 1024, 640, 640, 640, 0, 0, ZB);
    }

    // ---- encode ----
    {
        f16* E1h = WR;             f16* E1l = E1h + 3182592;
        f16* E2h = E1l + 3182592;  f16* E2l = E2h + 1572864;
        wt(enc_w1, 2072, 1536, E1h, E1l);
        wt(enc_w2, 1536, 1024, E2h, E2l);
        for (int rc = 1; rc <= 63; rc++) {
            const int Lo = 64 - rc, Li = Lo + 1;
            const int nch = (64 * Lo > 2016) ? 2 : 1, nb = 64 / nch;
            for (int c = 0; c < nch; c++) {
                const int b0 = c * nb, Mc = nb * Lo;
                const size_t ai = (size_t)b0 * Li * 1024;
                const size_t oi = (size_t)b0 * Lo * 1024;
                GEMM(1, 0, Xh + ai, Xl + ai, 1024, E1h, E1l, enc_b1,
                     Hh, Hl, (float*)0, Mc, 1536, 2072, 2080, 2048, Lo, Li, TS + rc * 32);
                ln(Hh, Hl, Hh, Hl, enc_g1, enc_bb1, Mc, 1536);
                GEMM(0, 0, Hh, Hl, 1536, E2h, E2l, enc_b2,
                     Xh + oi, Xl + oi, (float*)0, Mc, 1024, 1536, 1536, 1536, 0, 0, ZB);
                ln(Xh + oi, Xl + oi, Xh + oi, Xl + oi, enc_g2, enc_bb2, Mc, 1024);
            }
        }
    }

    // ---- decode ----
    {
        f16* D1h = WR;             f16* D1l = D1h + 1609728;
        f16* D2h = D1l + 1609728;  f16* D2l = D2h + 3145728;
        wt(dec_w1, 1048, 1536, D1h, D1l);
        wt(dec_w2, 1536, 2048, D2h, D2l);
        // first step: [64,1024] -> [64,2048] -> LN over [128,1024]
        GEMM(2, 0, Xh, Xl, 1024, D1h, D1l, dec_b1,
             Hh, Hl, (float*)0, 64, 1536, 1048, 1056, 1024, 0, 0, TS + 63 * 32);
        ln(Hh, Hl, Hh, Hl, dec_g1, dec_bb1, 64, 1536);
        GEMM(0, 0, Hh, Hl, 1536, D2h, D2l, dec_b2,
             Gh, Gl, (float*)0, 64, 2048, 1536, 1536, 1536, 0, 0, ZB);
        ln(Gh, Gl, Xh, Xl, d2_g, d2_b, 128, 1024);

        for (int rc = 62; rc >= 1; rc--) {
            const int Li = 64 - rc;
            const int nch = (64 * Li > 2016) ? 2 : 1, nb = 64 / nch;
            for (int c = nch - 1; c >= 0; c--) {        // high batches first
                const int b0 = c * nb, Mc = nb * Li;
                const size_t ai = (size_t)b0 * Li * 1024;
                const size_t oi = (size_t)b0 * (Li + 1) * 1024;
                GEMM(2, 0, Xh + ai, Xl + ai, 1024, D1h, D1l, dec_b1,
                     Hh, Hl, (float*)0, Mc, 1536, 1048, 1056, 1024, 0, 0, TS + rc * 32);
                ln(Hh, Hl, Hh, Hl, dec_g1, dec_bb1, Mc, 1536);
                GEMM(0, 0, Hh, Hl, 1536, D2h, D2l, dec_b2,
                     Gh, Gl, (float*)0, Mc, 2048, 1536, 1536, 1536, 0, 0, ZB);
                comb_ln_k<<<nb * (Li + 1), 256, 0, stream>>>(
                    Gh, Gl, Xh + oi, Xl + oi, d2_g, d2_b, Li);
            }
        }
    }

    // ---- descale_embedding ----
    {
        f16* W1h = WR;            f16* W1l = W1h + 655360;
        f16* W2h = W1l + 655360;  f16* W2l = W2h + 163840;
        wt(de_w1, 1024, 640, W1h, W1l);
        wt(de_w2, 640, 256, W2h, W2l);
        GEMM(0, 1, Xh, Xl, 1024, W1h, W1l, de_b1, Hh, Hl, (float*)0, 4096, 640, 1024, 1024, 1024, 0, 0, ZB);
        GEMM(0, 2, Hh, Hl, 640, W2h, W2l, de_b2, (f16*)0, (f16*)0, (float*)d_out, 4096, 256, 640, 640, 640, 0, 0, ZB);
    }
    #undef GEMM
}

// Round 3
// 24903.302 us; speedup vs baseline: 2.1552x; 1.4573x over previous
//
#include <hip/hip_runtime.h>

// ---------------------------------------------------------------------------
// RAE forward with split-f16 MFMA GEMMs + double-buffered (2-phase) staging.
// Every fp32 tensor value v is carried as f16 pair (hi, lo) with
//   v ~= hi + lo * 2^-12   (lo stored pre-scaled by 2^12)
// GEMM: C = A@W ~= Ah@Wh + (Al@Wh + Ah@Wl) * 2^-12   (3 MFMA products)
// ---------------------------------------------------------------------------

typedef _Float16 f16;
typedef _Float16 half8 __attribute__((ext_vector_type(8)));
typedef float floatx4 __attribute__((ext_vector_type(4)));

#define LO_SC   4096.0f
#define LO_ISC  2.44140625e-4f

__device__ __forceinline__ void gld_lds16(const f16* g, f16* l) {
    __builtin_amdgcn_global_load_lds(
        (const __attribute__((address_space(1))) void*)g,
        (__attribute__((address_space(3))) void*)l, 16, 0, 0);
}

__device__ __forceinline__ float pair_val(const f16* ph, const f16* pl, size_t i) {
    return (float)ph[i] + (float)pl[i] * LO_ISC;
}

__device__ __forceinline__ void split_store(float v, f16* ph, f16* pl, size_t i) {
    f16 h = (f16)v;
    ph[i] = h;
    pl[i] = (f16)((v - (float)h) * LO_SC);
}

// ----------------------------- GEMM ----------------------------------------
// MODE 0: plain A (pair arrays, row stride lda)
// MODE 1: enc-cat: logical row r -> b=r/Lo,l=r%Lo; A row = b*Li+l (2048-wide
//         contiguous window); k >= kbound -> ts table
// MODE 2: dec-cat: A row = r; k >= kbound -> ts table
// OUT 0: pair store; OUT 1: relu + pair store; OUT 2: fp32 store
// Tile 128x128, BK=32, 256 threads (4 waves), each wave a 64x64 quadrant.
// Double-buffered LDS: stage tile s+1 while computing tile s; single
// vmcnt-drain+barrier per K-step, positioned AFTER the MFMAs.
template<int MODE, int OUT>
__global__ __launch_bounds__(256, 2) void gemm_split(
    const f16* __restrict__ Ahi, const f16* __restrict__ Alo, int lda,
    const f16* __restrict__ Whi, const f16* __restrict__ Wlo,   // [N][K] transposed
    const float* __restrict__ bias,
    f16* __restrict__ Chi, f16* __restrict__ Clo, float* __restrict__ Cf,
    int M, int N, int K, int Kpad, int kbound, int Lo, int Li,
    const f16* __restrict__ tsrow, const f16* __restrict__ zrow)
{
    // [buf][arr: Ah,Al,Wh,Wl][kchunk][row][8]  -> 64 KiB total
    __shared__ __align__(16) f16 sm[2][4][4][128][8];

    const int tid  = threadIdx.x;
    const int lane = tid & 63;
    const int wid  = tid >> 6;
    const int bm   = blockIdx.y * 128;
    const int bn   = blockIdx.x * 128;

    // staging: wave `wid` fills kchunk = wid; slots it=0,1 -> row/col = it*64+lane
    const f16* aph[2]; const f16* apl[2];
    const f16* wph[2]; const f16* wpl[2];
    #pragma unroll
    for (int it = 0; it < 2; it++) {
        int r = bm + it * 64 + lane;
        if (r > M - 1) r = M - 1;
        int arow;
        if (MODE == 1) { int b = r / Lo; int l = r - b * Lo; arow = b * Li + l; }
        else arow = r;
        aph[it] = Ahi + (size_t)arow * lda;
        apl[it] = Alo + (size_t)arow * lda;
        int col = bn + it * 64 + lane;          // N % 128 == 0 -> in range
        wph[it] = Whi + (size_t)col * K;
        wpl[it] = Wlo + (size_t)col * K;
    }

    const int kw0 = wid * 8;
    auto stage = [&](int buf, int k0) {
        const int ka = k0 + kw0;
        int kwc = ka; if (kwc > K - 8) kwc = K - 8;   // W k-clamp (A side is 0 there)
        #pragma unroll
        for (int it = 0; it < 2; it++) {
            const f16* sh; const f16* sl;
            if (MODE == 0 || ka < kbound) { sh = aph[it] + ka; sl = apl[it] + ka; }
            else { sh = tsrow + (ka - kbound); sl = zrow; }
            gld_lds16(sh,            &sm[buf][0][wid][it * 64][0]);
            gld_lds16(sl,            &sm[buf][1][wid][it * 64][0]);
            gld_lds16(wph[it] + kwc, &sm[buf][2][wid][it * 64][0]);
            gld_lds16(wpl[it] + kwc, &sm[buf][3][wid][it * 64][0]);
        }
    };

    floatx4 acc1[4][4] = {};
    floatx4 acc2[4][4] = {};

    const int nsteps = Kpad >> 5;
    stage(0, 0);
    __syncthreads();                              // drain vmcnt; tile 0 ready

    const int kc = lane >> 4;
    const int fr = lane & 15;
    const int wr = (wid >> 1) * 64;
    const int wc = (wid & 1) * 64;

    for (int s = 0; s < nsteps; s++) {
        const int buf = s & 1;
        if (s + 1 < nsteps) stage(buf ^ 1, (s + 1) << 5);   // prefetch next tile

        half8 ah[4], al[4], wh[4], wl[4];
        #pragma unroll
        for (int m = 0; m < 4; m++) {
            ah[m] = *(const half8*)&sm[buf][0][kc][wr + m * 16 + fr][0];
            al[m] = *(const half8*)&sm[buf][1][kc][wr + m * 16 + fr][0];
        }
        #pragma unroll
        for (int n = 0; n < 4; n++) {
            wh[n] = *(const half8*)&sm[buf][2][kc][wc + n * 16 + fr][0];
            wl[n] = *(const half8*)&sm[buf][3][kc][wc + n * 16 + fr][0];
        }
        #pragma unroll
        for (int m = 0; m < 4; m++)
            #pragma unroll
            for (int n = 0; n < 4; n++) {
                acc1[m][n] = __builtin_amdgcn_mfma_f32_16x16x32_f16(ah[m], wh[n], acc1[m][n], 0, 0, 0);
                acc2[m][n] = __builtin_amdgcn_mfma_f32_16x16x32_f16(al[m], wh[n], acc2[m][n], 0, 0, 0);
                acc2[m][n] = __builtin_amdgcn_mfma_f32_16x16x32_f16(ah[m], wl[n], acc2[m][n], 0, 0, 0);
            }
        __syncthreads();   // vmcnt(0)+lgkmcnt(0) drain AFTER compute: prefetch hidden
    }

    // epilogue: C/D frag layout col = lane&15, row = (lane>>4)*4 + j
    const int q4  = (lane >> 4) * 4;
    #pragma unroll
    for (int n = 0; n < 4; n++) {
        const int gcol = bn + wc + n * 16 + fr;
        const float bv = bias[gcol];
        #pragma unroll
        for (int m = 0; m < 4; m++) {
            #pragma unroll
            for (int j = 0; j < 4; j++) {
                const int grow = bm + wr + m * 16 + q4 + j;
                if (grow < M) {
                    float v = acc1[m][n][j] + acc2[m][n][j] * LO_ISC + bv;
                    if (OUT == 1) v = fmaxf(v, 0.0f);
                    const size_t o = (size_t)grow * N + gcol;
                    if (OUT == 2) Cf[o] = v;
                    else {
                        f16 h = (f16)v;
                        Chi[o] = h;
                        Clo[o] = (f16)((v - (float)h) * LO_SC);
                    }
                }
            }
        }
    }
}

// --------------------------- LayerNorm + ReLU on pairs ----------------------
__global__ __launch_bounds__(256) void ln_pair_k(
    const f16* __restrict__ ih, const f16* __restrict__ il,
    f16* __restrict__ oh, f16* __restrict__ ol,
    const float* __restrict__ gw, const float* __restrict__ bw, int Wd)
{
    const size_t base = (size_t)blockIdx.x * Wd;
    const int nv = Wd >> 8;
    float vals[6], s = 0.f, s2 = 0.f;
    for (int i = 0; i < nv; i++) {
        int c = threadIdx.x + (i << 8);
        float v = pair_val(ih, il, base + c);
        vals[i] = v; s += v; s2 += v * v;
    }
    for (int o = 1; o < 64; o <<= 1) { s += __shfl_xor(s, o); s2 += __shfl_xor(s2, o); }
    __shared__ float red[2][4];
    if ((threadIdx.x & 63) == 0) { red[0][threadIdx.x >> 6] = s; red[1][threadIdx.x >> 6] = s2; }
    __syncthreads();
    s  = red[0][0] + red[0][1] + red[0][2] + red[0][3];
    s2 = red[1][0] + red[1][1] + red[1][2] + red[1][3];
    const float inv = 1.0f / (float)Wd;
    const float mean = s * inv;
    const float rstd = rsqrtf(s2 * inv - mean * mean + 1e-5f);
    for (int i = 0; i < nv; i++) {
        int c = threadIdx.x + (i << 8);
        float v = (vals[i] - mean) * rstd * gw[c] + bw[c];
        v = fmaxf(v, 0.0f);
        split_store(v, oh, ol, base + c);
    }
}

// ------------------- decode overlap-combine + LN + ReLU ---------------------
// G pair [nb*Liv, 2048] -> X pair rows [nb*(Liv+1), 1024]
__global__ __launch_bounds__(256) void comb_ln_k(
    const f16* __restrict__ gh, const f16* __restrict__ gl,
    f16* __restrict__ oh, f16* __restrict__ ol,
    const float* __restrict__ gw, const float* __restrict__ bw, int Liv)
{
    const int row = blockIdx.x;
    const int Lp = Liv + 1;
    const int b = row / Lp, j = row - b * Lp;
    float vals[4], s = 0.f, s2 = 0.f;
    for (int i = 0; i < 4; i++) {
        int c = threadIdx.x + (i << 8);
        float v;
        if (j == 0)          v = pair_val(gh, gl, (size_t)(b * Liv) * 2048 + c);
        else if (j == Liv)   v = pair_val(gh, gl, (size_t)(b * Liv + Liv - 1) * 2048 + 1024 + c);
        else v = 0.5f * (pair_val(gh, gl, (size_t)(b * Liv + j - 1) * 2048 + 1024 + c) +
                         pair_val(gh, gl, (size_t)(b * Liv + j) * 2048 + c));
        vals[i] = v; s += v; s2 += v * v;
    }
    for (int o = 1; o < 64; o <<= 1) { s += __shfl_xor(s, o); s2 += __shfl_xor(s2, o); }
    __shared__ float red[2][4];
    if ((threadIdx.x & 63) == 0) { red[0][threadIdx.x >> 6] = s; red[1][threadIdx.x >> 6] = s2; }
    __syncthreads();
    s  = red[0][0] + red[0][1] + red[0][2] + red[0][3];
    s2 = red[1][0] + red[1][1] + red[1][2] + red[1][3];
    const float mean = s * 9.765625e-4f;
    const float rstd = rsqrtf(s2 * 9.765625e-4f - mean * mean + 1e-5f);
    const size_t ob = (size_t)row * 1024;
    for (int i = 0; i < 4; i++) {
        int c = threadIdx.x + (i << 8);
        float v = (vals[i] - mean) * rstd * gw[c] + bw[c];
        v = fmaxf(v, 0.0f);
        split_store(v, oh, ol, ob + c);
    }
}

// ---------------- weight transpose + split: W[K][N] -> Wt[N][K] -------------
__global__ __launch_bounds__(256) void wt_split_k(
    const float* __restrict__ W, f16* __restrict__ Th, f16* __restrict__ Tl,
    int K, int N)
{
    __shared__ float t[64][65];
    const int k0 = blockIdx.x * 64, n0 = blockIdx.y * 64;
    {
        const int j = threadIdx.x & 63, i0 = (threadIdx.x >> 6) * 16;
        for (int ii = 0; ii < 16; ii++) {
            int k = k0 + i0 + ii;
            t[i0 + ii][j] = (k < K) ? W[(size_t)k * N + n0 + j] : 0.f;
        }
    }
    __syncthreads();
    const int i = threadIdx.x & 63, j0 = (threadIdx.x >> 6) * 16;
    const int k = k0 + i;
    if (k < K) {
        for (int jj = 0; jj < 16; jj++) {
            float v = t[i][j0 + jj];
            f16 h = (f16)v;
            const size_t o = (size_t)(n0 + j0 + jj) * K + k;
            Th[o] = h;
            Tl[o] = (f16)((v - (float)h) * LO_SC);
        }
    }
}

// --------------------------- misc small kernels -----------------------------
__global__ void split_x_k(const float* __restrict__ x, f16* __restrict__ h,
                          f16* __restrict__ l, int n) {
    int i = blockIdx.x * 256 + threadIdx.x;
    if (i < n) split_store(x[i], h, l, i);
}

__global__ void ts_init_k(f16* __restrict__ ts, f16* __restrict__ z) {
    int e = blockIdx.x * 256 + threadIdx.x;
    if (e < 2048) {
        int rc = e >> 5, c = e & 31;
        float v = 0.f;
        if (rc >= 1) {
            int idx = (rc == 1) ? 1 : (rc == 2) ? 2 : (rc <= 4) ? 3 : ((rc + 10) / 3 - 1);
            if (c == 0) v = (float)rc;
            else if (c == idx) v = 1.f;
        }
        ts[e] = (f16)v;
    }
    if (e < 32) z[e] = (f16)0.f;
}

// ------------------------------ orchestration -------------------------------
extern "C" void kernel_launch(void* const* d_in, const int* in_sizes, int n_in,
                              void* d_out, int out_size, void* d_ws, size_t ws_size,
                              hipStream_t stream)
{
    const float* xin    = (const float*)d_in[0];
    const float* se_w1  = (const float*)d_in[1];
    const float* se_b1  = (const float*)d_in[2];
    const float* se_w2  = (const float*)d_in[3];
    const float* se_b2  = (const float*)d_in[4];
    const float* enc_w1 = (const float*)d_in[5];
    const float* enc_b1 = (const float*)d_in[6];
    const float* enc_g1 = (const float*)d_in[7];
    const float* enc_bb1= (const float*)d_in[8];
    const float* enc_w2 = (const float*)d_in[9];
    const float* enc_b2 = (const float*)d_in[10];
    const float* enc_g2 = (const float*)d_in[11];
    const float* enc_bb2= (const float*)d_in[12];
    const float* dec_w1 = (const float*)d_in[13];
    const float* dec_b1 = (const float*)d_in[14];
    const float* dec_g1 = (const float*)d_in[15];
    const float* dec_bb1= (const float*)d_in[16];
    const float* dec_w2 = (const float*)d_in[17];
    const float* dec_b2 = (const float*)d_in[18];
    const float* d2_g   = (const float*)d_in[19];
    const float* d2_b   = (const float*)d_in[20];
    const float* de_w1  = (const float*)d_in[21];
    const float* de_b1  = (const float*)d_in[22];
    const float* de_w2  = (const float*)d_in[23];
    const float* de_b2  = (const float*)d_in[24];

    // ---------------- workspace layout (f16 units) ----------------
    // X: 2 x 4,194,304
    // V: variable region — small 14,450,688 / big 28,901,376
    // WR: 9,510,912 ; TS: 2048 ; ZB: 32
    const bool big = ws_size >= 93605952ull;     // big layout total bytes
    const size_t VSZ = big ? 28901376u : 14450688u;

    f16* ws = (f16*)d_ws;
    f16* Xh = ws;
    f16* Xl = Xh + 4194304;
    f16* V  = Xl + 4194304;
    f16* WR = V + VSZ;
    f16* TS = WR + 9510912;
    f16* ZB = TS + 2048;

    ts_init_k<<<8, 256, 0, stream>>>(TS, ZB);

    auto wt = [&](const float* W, int K, int N, f16* Th, f16* Tl) {
        wt_split_k<<<dim3((K + 63) / 64, N / 64), 256, 0, stream>>>(W, Th, Tl, K, N);
    };
    auto ln = [&](const f16* ih, const f16* il, f16* oh, f16* ol,
                  const float* g, const float* b, int rows, int Wd) {
        ln_pair_k<<<rows, 256, 0, stream>>>(ih, il, oh, ol, g, b, Wd);
    };

    #define GEMM(MODE, OUT, Ah, Al, lda, Wh, Wl, bias, Ch, Cl, Cf, M, N, K, Kpad, kb, Lo, Li, tsr) \
        gemm_split<MODE, OUT><<<dim3((N) / 128, ((M) + 127) / 128), 256, 0, stream>>>( \
            Ah, Al, lda, Wh, Wl, bias, Ch, Cl, Cf, M, N, K, Kpad, kb, Lo, Li, tsr, ZB)

    // ---- scale_embedding ----
    {
        f16* W1h = WR;            f16* W1l = W1h + 163840;
        f16* W2h = W1l + 163840;  f16* W2l = W2h + 655360;
        wt(se_w1, 256, 640, W1h, W1l);
        wt(se_w2, 640, 1024, W2h, W2l);
        f16* Sh  = V;             f16* Sl  = V + 1048576;
        f16* H1h = V + 2097152;   f16* H1l = V + 4718592;   // 4096x640 pairs
        split_x_k<<<4096, 256, 0, stream>>>(xin, Sh, Sl, 1048576);
        GEMM(0, 1, Sh, Sl, 256, W1h, W1l, se_b1, H1h, H1l, (float*)0, 4096, 640, 256, 256, 256, 0, 0, ZB);
        GEMM(0, 1, H1h, H1l, 640, W2h, W2l, se_b2, Xh, Xl, (float*)0, 4096, 1024, 640, 640, 640, 0, 0, ZB);
    }

    // ---- encode (always unchunked: H spans V, needs 2 x 6,193,152 <= VSZ) ----
    {
        f16* E1h = WR;             f16* E1l = E1h + 3182592;
        f16* E2h = E1l + 3182592;  f16* E2l = E2h + 1572864;
        wt(enc_w1, 2072, 1536, E1h, E1l);
        wt(enc_w2, 1536, 1024, E2h, E2l);
        f16* Hh = V; f16* Hl = V + 6193152;
        for (int rc = 1; rc <= 63; rc++) {
            const int Lo = 64 - rc, Li = Lo + 1, Mc = 64 * Lo;
            GEMM(1, 0, Xh, Xl, 1024, E1h, E1l, enc_b1,
                 Hh, Hl, (float*)0, Mc, 1536, 2072, 2080, 2048, Lo, Li, TS + rc * 32);
            ln(Hh, Hl, Hh, Hl, enc_g1, enc_bb1, Mc, 1536);
            GEMM(0, 0, Hh, Hl, 1536, E2h, E2l, enc_b2,
                 Xh, Xl, (float*)0, Mc, 1024, 1536, 1536, 1536, 0, 0, ZB);
            ln(Xh, Xl, Xh, Xl, enc_g2, enc_bb2, Mc, 1024);
        }
    }

    // ---- decode ----
    {
        f16* D1h = WR;             f16* D1l = D1h + 1609728;
        f16* D2h = D1l + 1609728;  f16* D2l = D2h + 3145728;
        wt(dec_w1, 1048, 1536, D1h, D1l);
        wt(dec_w2, 1536, 2048, D2h, D2l);

        f16 *Hh, *Hl, *Gh, *Gl;
        if (big) { Hh = V; Hl = V + 6193152; Gh = V + 12386304; Gl = V + 20643840; }
        else     { Hh = V; Hl = V + 3096576; Gh = V + 6193152;  Gl = V + 10321920; }

        // first step: [64,1024] -> [64,2048] -> LN over [128,1024]
        GEMM(2, 0, Xh, Xl, 1024, D1h, D1l, dec_b1,
             Hh, Hl, (float*)0, 64, 1536, 1048, 1056, 1024, 0, 0, TS + 63 * 32);
        ln(Hh, Hl, Hh, Hl, dec_g1, dec_bb1, 64, 1536);
        GEMM(0, 0, Hh, Hl, 1536, D2h, D2l, dec_b2,
             Gh, Gl, (float*)0, 64, 2048, 1536, 1536, 1536, 0, 0, ZB);
        ln(Gh, Gl, Xh, Xl, d2_g, d2_b, 128, 1024);

        for (int rc = 62; rc >= 1; rc--) {
            const int Li = 64 - rc;
            const int nch = (!big && 64 * Li > 2016) ? 2 : 1, nb = 64 / nch;
            for (int c = nch - 1; c >= 0; c--) {        // high batches first
                const int b0 = c * nb, Mc = nb * Li;
                const size_t ai = (size_t)b0 * Li * 1024;
                const size_t oi = (size_t)b0 * (Li + 1) * 1024;
                GEMM(2, 0, Xh + ai, Xl + ai, 1024, D1h, D1l, dec_b1,
                     Hh, Hl, (float*)0, Mc, 1536, 1048, 1056, 1024, 0, 0, TS + rc * 32);
                ln(Hh, Hl, Hh, Hl, dec_g1, dec_bb1, Mc, 1536);
                GEMM(0, 0, Hh, Hl, 1536, D2h, D2l, dec_b2,
                     Gh, Gl, (float*)0, Mc, 2048, 1536, 1536, 1536, 0, 0, ZB);
                comb_ln_k<<<nb * (Li + 1), 256, 0, stream>>>(
                    Gh, Gl, Xh + oi, Xl + oi, d2_g, d2_b, Li);
            }
        }
    }

    // ---- descale_embedding ----
    {
        f16* W1h = WR;            f16* W1l = W1h + 655360;
        f16* W2h = W1l + 655360;  f16* W2l = W2h + 163840;
        wt(de_w1, 1024, 640, W1h, W1l);
        wt(de_w2, 640, 256, W2h, W2l);
        f16* H1h = V;             f16* H1l = V + 2621440;   // 4096x640 pairs
        GEMM(0, 1, Xh, Xl, 1024, W1h, W1l, de_b1, H1h, H1l, (float*)0, 4096, 640, 1024, 1024, 1024, 0, 0, ZB);
        GEMM(0, 2, H1h, H1l, 640, W2h, W2l, de_b2, (f16*)0, (f16*)0, (float*)d_out, 4096, 256, 640, 640, 640, 0, 0, ZB);
    }
    #undef GEMM
}

// Round 4
// 24163.701 us; speedup vs baseline: 2.2212x; 1.0306x over previous
//
#include <hip/hip_runtime.h>

// ---------------------------------------------------------------------------
// RAE forward with split-f16 MFMA GEMMs + double-buffered staging +
// XCD-aware (column-chunked, bijective) block swizzle + vectorized LN.
// Every fp32 tensor value v is carried as f16 pair (hi, lo) with
//   v ~= hi + lo * 2^-12   (lo stored pre-scaled by 2^12)
// GEMM: C = A@W ~= Ah@Wh + (Al@Wh + Ah@Wl) * 2^-12   (3 MFMA products)
// ---------------------------------------------------------------------------

typedef _Float16 f16;
typedef _Float16 half8 __attribute__((ext_vector_type(8)));
typedef float floatx4 __attribute__((ext_vector_type(4)));

#define LO_SC   4096.0f
#define LO_ISC  2.44140625e-4f

__device__ __forceinline__ void gld_lds16(const f16* g, f16* l) {
    __builtin_amdgcn_global_load_lds(
        (const __attribute__((address_space(1))) void*)g,
        (__attribute__((address_space(3))) void*)l, 16, 0, 0);
}

__device__ __forceinline__ float pair_val(const f16* ph, const f16* pl, size_t i) {
    return (float)ph[i] + (float)pl[i] * LO_ISC;
}

// ----------------------------- GEMM ----------------------------------------
// MODE 0: plain A. MODE 1: enc-cat (row b*Li+l, 2048-wide window; k>=kbound ->
// ts table). MODE 2: dec-cat (k>=kbound -> ts table).
// OUT 0: pair store; OUT 1: relu + pair store; OUT 2: fp32 store.
// Tile 128x128, BK=32, 256 threads (4 waves). 1-D grid of gy*gx blocks,
// column-major-chunked XCD swizzle: XCD k owns a contiguous bx-major rank
// chunk -> its W-panel slice stays L2-resident across all steps of a phase.
template<int MODE, int OUT>
__global__ __launch_bounds__(256, 2) void gemm_split(
    const f16* __restrict__ Ahi, const f16* __restrict__ Alo, int lda,
    const f16* __restrict__ Whi, const f16* __restrict__ Wlo,   // [N][K] transposed
    const float* __restrict__ bias,
    f16* __restrict__ Chi, f16* __restrict__ Clo, float* __restrict__ Cf,
    int M, int N, int K, int Kpad, int kbound, int Lo, int Li,
    const f16* __restrict__ tsrow, const f16* __restrict__ zrow,
    int gy, int q, int r)
{
    // [buf][arr: Ah,Al,Wh,Wl][kchunk][row][8]  -> 64 KiB total
    __shared__ __align__(16) f16 sm[2][4][4][128][8];

    const int tid  = threadIdx.x;
    const int lane = tid & 63;
    const int wid  = tid >> 6;

    // bijective XCD swizzle (m204): hardware places consecutive ids
    // round-robin over 8 XCDs; rank is bx-major so each XCD gets a
    // contiguous run of N-columns.
    const int bid = blockIdx.x;
    const int xcd = bid & 7, jj = bid >> 3;
    const int rank = (xcd < r) ? xcd * (q + 1) + jj
                               : r * (q + 1) + (xcd - r) * q + jj;
    const int bx = rank / gy, by = rank - bx * gy;
    const int bm = by * 128;
    const int bn = bx * 128;

    // staging: wave `wid` fills kchunk = wid; slots it=0,1 -> row/col = it*64+lane
    const f16* aph[2]; const f16* apl[2];
    const f16* wph[2]; const f16* wpl[2];
    #pragma unroll
    for (int it = 0; it < 2; it++) {
        int rr = bm + it * 64 + lane;
        if (rr > M - 1) rr = M - 1;
        int arow;
        if (MODE == 1) { int b = rr / Lo; int l = rr - b * Lo; arow = b * Li + l; }
        else arow = rr;
        aph[it] = Ahi + (size_t)arow * lda;
        apl[it] = Alo + (size_t)arow * lda;
        int col = bn + it * 64 + lane;          // N % 128 == 0 -> in range
        wph[it] = Whi + (size_t)col * K;
        wpl[it] = Wlo + (size_t)col * K;
    }

    const int kw0 = wid * 8;
    auto stage = [&](int buf, int k0) {
        const int ka = k0 + kw0;
        int kwc = ka; if (kwc > K - 8) kwc = K - 8;   // W k-clamp (A side is 0 there)
        #pragma unroll
        for (int it = 0; it < 2; it++) {
            const f16* sh; const f16* sl;
            if (MODE == 0 || ka < kbound) { sh = aph[it] + ka; sl = apl[it] + ka; }
            else { sh = tsrow + (ka - kbound); sl = zrow; }
            gld_lds16(sh,            &sm[buf][0][wid][it * 64][0]);
            gld_lds16(sl,            &sm[buf][1][wid][it * 64][0]);
            gld_lds16(wph[it] + kwc, &sm[buf][2][wid][it * 64][0]);
            gld_lds16(wpl[it] + kwc, &sm[buf][3][wid][it * 64][0]);
        }
    };

    floatx4 acc1[4][4] = {};
    floatx4 acc2[4][4] = {};

    const int nsteps = Kpad >> 5;
    stage(0, 0);
    __syncthreads();                              // drain vmcnt; tile 0 ready

    const int kc = lane >> 4;
    const int fr = lane & 15;
    const int wr = (wid >> 1) * 64;
    const int wc = (wid & 1) * 64;

    for (int s = 0; s < nsteps; s++) {
        const int buf = s & 1;
        if (s + 1 < nsteps) stage(buf ^ 1, (s + 1) << 5);   // prefetch next tile

        half8 ah[4], al[4], wh[4], wl[4];
        #pragma unroll
        for (int m = 0; m < 4; m++) {
            ah[m] = *(const half8*)&sm[buf][0][kc][wr + m * 16 + fr][0];
            al[m] = *(const half8*)&sm[buf][1][kc][wr + m * 16 + fr][0];
        }
        #pragma unroll
        for (int n = 0; n < 4; n++) {
            wh[n] = *(const half8*)&sm[buf][2][kc][wc + n * 16 + fr][0];
            wl[n] = *(const half8*)&sm[buf][3][kc][wc + n * 16 + fr][0];
        }
        #pragma unroll
        for (int m = 0; m < 4; m++)
            #pragma unroll
            for (int n = 0; n < 4; n++) {
                acc1[m][n] = __builtin_amdgcn_mfma_f32_16x16x32_f16(ah[m], wh[n], acc1[m][n], 0, 0, 0);
                acc2[m][n] = __builtin_amdgcn_mfma_f32_16x16x32_f16(al[m], wh[n], acc2[m][n], 0, 0, 0);
                acc2[m][n] = __builtin_amdgcn_mfma_f32_16x16x32_f16(ah[m], wl[n], acc2[m][n], 0, 0, 0);
            }
        __syncthreads();   // vmcnt+lgkm drain AFTER compute: prefetch hidden
    }

    // epilogue: C/D frag layout col = lane&15, row = (lane>>4)*4 + j
    const int q4  = (lane >> 4) * 4;
    #pragma unroll
    for (int n = 0; n < 4; n++) {
        const int gcol = bn + wc + n * 16 + fr;
        const float bv = bias[gcol];
        #pragma unroll
        for (int m = 0; m < 4; m++) {
            #pragma unroll
            for (int j = 0; j < 4; j++) {
                const int grow = bm + wr + m * 16 + q4 + j;
                if (grow < M) {
                    float v = acc1[m][n][j] + acc2[m][n][j] * LO_ISC + bv;
                    if (OUT == 1) v = fmaxf(v, 0.0f);
                    const size_t o = (size_t)grow * N + gcol;
                    if (OUT == 2) Cf[o] = v;
                    else {
                        f16 h = (f16)v;
                        Chi[o] = h;
                        Clo[o] = (f16)((v - (float)h) * LO_SC);
                    }
                }
            }
        }
    }
}

// ------------------ LayerNorm + ReLU on pairs (vectorized) ------------------
// block = Wd/8 threads (128/192/256); each thread one half8 per array.
__global__ void ln_pair_v(
    const f16* __restrict__ ih, const f16* __restrict__ il,
    f16* __restrict__ oh, f16* __restrict__ ol,
    const float* __restrict__ gw, const float* __restrict__ bw, int Wd)
{
    const size_t base = (size_t)blockIdx.x * Wd;
    const int i8 = threadIdx.x * 8;
    half8 hv = *(const half8*)(ih + base + i8);
    half8 lv = *(const half8*)(il + base + i8);
    float v[8], s = 0.f, s2 = 0.f;
    #pragma unroll
    for (int k = 0; k < 8; k++) {
        v[k] = (float)hv[k] + (float)lv[k] * LO_ISC;
        s += v[k]; s2 += v[k] * v[k];
    }
    #pragma unroll
    for (int o = 1; o < 64; o <<= 1) { s += __shfl_xor(s, o); s2 += __shfl_xor(s2, o); }
    __shared__ float red[2][4];
    const int nw = blockDim.x >> 6;
    if ((threadIdx.x & 63) == 0) { red[0][threadIdx.x >> 6] = s; red[1][threadIdx.x >> 6] = s2; }
    __syncthreads();
    s = 0.f; s2 = 0.f;
    for (int w = 0; w < nw; w++) { s += red[0][w]; s2 += red[1][w]; }
    const float inv = 1.0f / (float)Wd;
    const float mean = s * inv;
    const float rstd = rsqrtf(s2 * inv - mean * mean + 1e-5f);
    const float4 g0 = *(const float4*)(gw + i8), g1 = *(const float4*)(gw + i8 + 4);
    const float4 b0 = *(const float4*)(bw + i8), b1 = *(const float4*)(bw + i8 + 4);
    const float gg[8] = {g0.x, g0.y, g0.z, g0.w, g1.x, g1.y, g1.z, g1.w};
    const float bb[8] = {b0.x, b0.y, b0.z, b0.w, b1.x, b1.y, b1.z, b1.w};
    half8 ho, lo_;
    #pragma unroll
    for (int k = 0; k < 8; k++) {
        float y = fmaxf((v[k] - mean) * rstd * gg[k] + bb[k], 0.0f);
        f16 h = (f16)y;
        ho[k] = h; lo_[k] = (f16)((y - (float)h) * LO_SC);
    }
    *(half8*)(oh + base + i8) = ho;
    *(half8*)(ol + base + i8) = lo_;
}

// --------- decode overlap-combine + LN + ReLU (vectorized, Wd=1024) ---------
__global__ void comb_ln_v(
    const f16* __restrict__ gh, const f16* __restrict__ gl,
    f16* __restrict__ oh, f16* __restrict__ ol,
    const float* __restrict__ gw, const float* __restrict__ bw, int Liv)
{
    const int row = blockIdx.x;
    const int Lp = Liv + 1;
    const int b = row / Lp, j = row - b * Lp;
    const int i8 = threadIdx.x * 8;
    float v[8], s = 0.f, s2 = 0.f;
    if (j == 0 || j == Liv) {
        const size_t off = (j == 0) ? (size_t)(b * Liv) * 2048 + i8
                                    : (size_t)(b * Liv + Liv - 1) * 2048 + 1024 + i8;
        half8 hv = *(const half8*)(gh + off);
        half8 lv = *(const half8*)(gl + off);
        #pragma unroll
        for (int k = 0; k < 8; k++) v[k] = (float)hv[k] + (float)lv[k] * LO_ISC;
    } else {
        const size_t o1 = (size_t)(b * Liv + j - 1) * 2048 + 1024 + i8;
        const size_t o2 = (size_t)(b * Liv + j) * 2048 + i8;
        half8 h1 = *(const half8*)(gh + o1), l1 = *(const half8*)(gl + o1);
        half8 h2 = *(const half8*)(gh + o2), l2 = *(const half8*)(gl + o2);
        #pragma unroll
        for (int k = 0; k < 8; k++)
            v[k] = 0.5f * (((float)h1[k] + (float)l1[k] * LO_ISC) +
                           ((float)h2[k] + (float)l2[k] * LO_ISC));
    }
    #pragma unroll
    for (int k = 0; k < 8; k++) { s += v[k]; s2 += v[k] * v[k]; }
    #pragma unroll
    for (int o = 1; o < 64; o <<= 1) { s += __shfl_xor(s, o); s2 += __shfl_xor(s2, o); }
    __shared__ float red[2][2];
    if ((threadIdx.x & 63) == 0) { red[0][threadIdx.x >> 6] = s; red[1][threadIdx.x >> 6] = s2; }
    __syncthreads();
    s = red[0][0] + red[0][1]; s2 = red[1][0] + red[1][1];
    const float mean = s * 9.765625e-4f;
    const float rstd = rsqrtf(s2 * 9.765625e-4f - mean * mean + 1e-5f);
    const float4 g0 = *(const float4*)(gw + i8), g1 = *(const float4*)(gw + i8 + 4);
    const float4 b0 = *(const float4*)(bw + i8), b1 = *(const float4*)(bw + i8 + 4);
    const float gg[8] = {g0.x, g0.y, g0.z, g0.w, g1.x, g1.y, g1.z, g1.w};
    const float bb[8] = {b0.x, b0.y, b0.z, b0.w, b1.x, b1.y, b1.z, b1.w};
    const size_t ob = (size_t)row * 1024 + i8;
    half8 ho, lo_;
    #pragma unroll
    for (int k = 0; k < 8; k++) {
        float y = fmaxf((v[k] - mean) * rstd * gg[k] + bb[k], 0.0f);
        f16 h = (f16)y;
        ho[k] = h; lo_[k] = (f16)((y - (float)h) * LO_SC);
    }
    *(half8*)(oh + ob) = ho;
    *(half8*)(ol + ob) = lo_;
}

// ---------------- weight transpose + split: W[K][N] -> Wt[N][K] -------------
__global__ __launch_bounds__(256) void wt_split_k(
    const float* __restrict__ W, f16* __restrict__ Th, f16* __restrict__ Tl,
    int K, int N)
{
    __shared__ float t[64][65];
    const int k0 = blockIdx.x * 64, n0 = blockIdx.y * 64;
    {
        const int j = threadIdx.x & 63, i0 = (threadIdx.x >> 6) * 16;
        for (int ii = 0; ii < 16; ii++) {
            int k = k0 + i0 + ii;
            t[i0 + ii][j] = (k < K) ? W[(size_t)k * N + n0 + j] : 0.f;
        }
    }
    __syncthreads();
    const int i = threadIdx.x & 63, j0 = (threadIdx.x >> 6) * 16;
    const int k = k0 + i;
    if (k < K) {
        for (int jj = 0; jj < 16; jj++) {
            float v = t[i][j0 + jj];
            f16 h = (f16)v;
            const size_t o = (size_t)(n0 + j0 + jj) * K + k;
            Th[o] = h;
            Tl[o] = (f16)((v - (float)h) * LO_SC);
        }
    }
}

// --------------------------- misc small kernels -----------------------------
__global__ void split_x_v(const float* __restrict__ x, f16* __restrict__ h,
                          f16* __restrict__ l, int n8) {
    int i = blockIdx.x * 256 + threadIdx.x;
    if (i >= n8) return;
    const int i8 = i * 8;
    const float4 f0 = *(const float4*)(x + i8), f1 = *(const float4*)(x + i8 + 4);
    const float vv[8] = {f0.x, f0.y, f0.z, f0.w, f1.x, f1.y, f1.z, f1.w};
    half8 ho, lo_;
    #pragma unroll
    for (int k = 0; k < 8; k++) {
        f16 hh = (f16)vv[k];
        ho[k] = hh; lo_[k] = (f16)((vv[k] - (float)hh) * LO_SC);
    }
    *(half8*)(h + i8) = ho;
    *(half8*)(l + i8) = lo_;
}

__global__ void ts_init_k(f16* __restrict__ ts, f16* __restrict__ z) {
    int e = blockIdx.x * 256 + threadIdx.x;
    if (e < 2048) {
        int rc = e >> 5, c = e & 31;
        float v = 0.f;
        if (rc >= 1) {
            int idx = (rc == 1) ? 1 : (rc == 2) ? 2 : (rc <= 4) ? 3 : ((rc + 10) / 3 - 1);
            if (c == 0) v = (float)rc;
            else if (c == idx) v = 1.f;
        }
        ts[e] = (f16)v;
    }
    if (e < 32) z[e] = (f16)0.f;
}

// ------------------------------ orchestration -------------------------------
extern "C" void kernel_launch(void* const* d_in, const int* in_sizes, int n_in,
                              void* d_out, int out_size, void* d_ws, size_t ws_size,
                              hipStream_t stream)
{
    const float* xin    = (const float*)d_in[0];
    const float* se_w1  = (const float*)d_in[1];
    const float* se_b1  = (const float*)d_in[2];
    const float* se_w2  = (const float*)d_in[3];
    const float* se_b2  = (const float*)d_in[4];
    const float* enc_w1 = (const float*)d_in[5];
    const float* enc_b1 = (const float*)d_in[6];
    const float* enc_g1 = (const float*)d_in[7];
    const float* enc_bb1= (const float*)d_in[8];
    const float* enc_w2 = (const float*)d_in[9];
    const float* enc_b2 = (const float*)d_in[10];
    const float* enc_g2 = (const float*)d_in[11];
    const float* enc_bb2= (const float*)d_in[12];
    const float* dec_w1 = (const float*)d_in[13];
    const float* dec_b1 = (const float*)d_in[14];
    const float* dec_g1 = (const float*)d_in[15];
    const float* dec_bb1= (const float*)d_in[16];
    const float* dec_w2 = (const float*)d_in[17];
    const float* dec_b2 = (const float*)d_in[18];
    const float* d2_g   = (const float*)d_in[19];
    const float* d2_b   = (const float*)d_in[20];
    const float* de_w1  = (const float*)d_in[21];
    const float* de_b1  = (const float*)d_in[22];
    const float* de_w2  = (const float*)d_in[23];
    const float* de_b2  = (const float*)d_in[24];

    // ---------------- workspace layout (f16 units) ----------------
    const bool big = ws_size >= 93605952ull;     // big layout total bytes
    const size_t VSZ = big ? 28901376u : 14450688u;

    f16* ws = (f16*)d_ws;
    f16* Xh = ws;
    f16* Xl = Xh + 4194304;
    f16* V  = Xl + 4194304;
    f16* WR = V + VSZ;
    f16* TS = WR + 9510912;
    f16* ZB = TS + 2048;

    ts_init_k<<<8, 256, 0, stream>>>(TS, ZB);

    auto wt = [&](const float* W, int K, int N, f16* Th, f16* Tl) {
        wt_split_k<<<dim3((K + 63) / 64, N / 64), 256, 0, stream>>>(W, Th, Tl, K, N);
    };
    auto ln = [&](const f16* ih, const f16* il, f16* oh, f16* ol,
                  const float* g, const float* b, int rows, int Wd) {
        ln_pair_v<<<rows, Wd / 8, 0, stream>>>(ih, il, oh, ol, g, b, Wd);
    };

    #define GEMM(MODE, OUT, Ah, Al, lda, Wh, Wl, bias, Ch, Cl, Cf, M, N, K, Kpad, kb, Lo, Li, tsr) \
        do { \
            const int gx_ = (N) / 128, gy_ = ((M) + 127) / 128;            \
            const int nwg_ = gx_ * gy_, q_ = nwg_ >> 3, r_ = nwg_ & 7;     \
            gemm_split<MODE, OUT><<<nwg_, 256, 0, stream>>>(               \
                Ah, Al, lda, Wh, Wl, bias, Ch, Cl, Cf, M, N, K, Kpad, kb,  \
                Lo, Li, tsr, ZB, gy_, q_, r_);                             \
        } while (0)

    // ---- scale_embedding ----
    {
        f16* W1h = WR;            f16* W1l = W1h + 163840;
        f16* W2h = W1l + 163840;  f16* W2l = W2h + 655360;
        wt(se_w1, 256, 640, W1h, W1l);
        wt(se_w2, 640, 1024, W2h, W2l);
        f16* Sh  = V;             f16* Sl  = V + 1048576;
        f16* H1h = V + 2097152;   f16* H1l = V + 4718592;   // 4096x640 pairs
        split_x_v<<<512, 256, 0, stream>>>(xin, Sh, Sl, 131072);
        GEMM(0, 1, Sh, Sl, 256, W1h, W1l, se_b1, H1h, H1l, (float*)0, 4096, 640, 256, 256, 256, 0, 0, ZB);
        GEMM(0, 1, H1h, H1l, 640, W2h, W2l, se_b2, Xh, Xl, (float*)0, 4096, 1024, 640, 640, 640, 0, 0, ZB);
    }

    // ---- encode (unchunked: H spans V) ----
    {
        f16* E1h = WR;             f16* E1l = E1h + 3182592;
        f16* E2h = E1l + 3182592;  f16* E2l = E2h + 1572864;
        wt(enc_w1, 2072, 1536, E1h, E1l);
        wt(enc_w2, 1536, 1024, E2h, E2l);
        f16* Hh = V; f16* Hl = V + 6193152;
        for (int rc = 1; rc <= 63; rc++) {
            const int Lo = 64 - rc, Li = Lo + 1, Mc = 64 * Lo;
            GEMM(1, 0, Xh, Xl, 1024, E1h, E1l, enc_b1,
                 Hh, Hl, (float*)0, Mc, 1536, 2072, 2080, 2048, Lo, Li, TS + rc * 32);
            ln(Hh, Hl, Hh, Hl, enc_g1, enc_bb1, Mc, 1536);
            GEMM(0, 0, Hh, Hl, 1536, E2h, E2l, enc_b2,
                 Xh, Xl, (float*)0, Mc, 1024, 1536, 1536, 1536, 0, 0, ZB);
            ln(Xh, Xl, Xh, Xl, enc_g2, enc_bb2, Mc, 1024);
        }
    }

    // ---- decode ----
    {
        f16* D1h = WR;             f16* D1l = D1h + 1609728;
        f16* D2h = D1l + 1609728;  f16* D2l = D2h + 3145728;
        wt(dec_w1, 1048, 1536, D1h, D1l);
        wt(dec_w2, 1536, 2048, D2h, D2l);

        f16 *Hh, *Hl, *Gh, *Gl;
        if (big) { Hh = V; Hl = V + 6193152; Gh = V + 12386304; Gl = V + 20643840; }
        else     { Hh = V; Hl = V + 3096576; Gh = V + 6193152;  Gl = V + 10321920; }

        // first step: [64,1024] -> [64,2048] -> LN over [128,1024]
        GEMM(2, 0, Xh, Xl, 1024, D1h, D1l, dec_b1,
             Hh, Hl, (float*)0, 64, 1536, 1048, 1056, 1024, 0, 0, TS + 63 * 32);
        ln(Hh, Hl, Hh, Hl, dec_g1, dec_bb1, 64, 1536);
        GEMM(0, 0, Hh, Hl, 1536, D2h, D2l, dec_b2,
             Gh, Gl, (float*)0, 64, 2048, 1536, 1536, 1536, 0, 0, ZB);
        ln(Gh, Gl, Xh, Xl, d2_g, d2_b, 128, 1024);

        for (int rc = 62; rc >= 1; rc--) {
            const int Li = 64 - rc;
            const int nch = (!big && 64 * Li > 2016) ? 2 : 1, nb = 64 / nch;
            for (int c = nch - 1; c >= 0; c--) {        // high batches first
                const int b0 = c * nb, Mc = nb * Li;
                const size_t ai = (size_t)b0 * Li * 1024;
                const size_t oi = (size_t)b0 * (Li + 1) * 1024;
                GEMM(2, 0, Xh + ai, Xl + ai, 1024, D1h, D1l, dec_b1,
                     Hh, Hl, (float*)0, Mc, 1536, 1048, 1056, 1024, 0, 0, TS + rc * 32);
                ln(Hh, Hl, Hh, Hl, dec_g1, dec_bb1, Mc, 1536);
                GEMM(0, 0, Hh, Hl, 1536, D2h, D2l, dec_b2,
                     Gh, Gl, (float*)0, Mc, 2048, 1536, 1536, 1536, 0, 0, ZB);
                comb_ln_v<<<nb * (Li + 1), 128, 0, stream>>>(
                    Gh, Gl, Xh + oi, Xl + oi, d2_g, d2_b, Li);
            }
        }
    }

    // ---- descale_embedding ----
    {
        f16* W1h = WR;            f16* W1l = W1h + 655360;
        f16* W2h = W1l + 655360;  f16* W2l = W2h + 163840;
        wt(de_w1, 1024, 640, W1h, W1l);
        wt(de_w2, 640, 256, W2h, W2l);
        f16* H1h = V;             f16* H1l = V + 2621440;   // 4096x640 pairs
        GEMM(0, 1, Xh, Xl, 1024, W1h, W1l, de_b1, H1h, H1l, (float*)0, 4096, 640, 1024, 1024, 1024, 0, 0, ZB);
        GEMM(0, 2, H1h, H1l, 640, W2h, W2l, de_b2, (f16*)0, (f16*)0, (float*)d_out, 4096, 256, 640, 640, 640, 0, 0, ZB);
    }
    #undef GEMM
}